// Round 6
// baseline (1584.215 us; speedup 1.0000x reference)
//
#include <hip/hip_runtime.h>
#include <hip/hip_bf16.h>

// ---------------------------------------------------------------------------
// Bidirectional GRU encoder (Keras reset_after=true), B=64 S=512 U=256 V=32000
// Round 6: MFMA-based recurrence.
//   k0a wt_prep : W fp32 -> Wtb [dir][768][256] bf16 (transposed)
//   k0b u_prep  : U fp32 -> Upk MFMA B-fragment blobs [dir][w][slot][kk][lane][8]
//   k0c xmask   : mask bitmap per timestep (64 batches -> u64)
//   k1  gx_mfma : gx3 = emb[x] @ W + b_in (+ b_rec for z,r), stored bf16 in the
//                 exact per-(dir,t,bg,w,slot,lane,q) order k2's epilogue reads
//   k2  gru     : 8 wgs = (dir, 16-batch group), 512 thr / 8 waves, lb(512,2).
//                 Wave owns units [w*32,w*32+32): slots z0,z1,r0,r1,h0,h1.
//                 U resident as 48 short8 B-frags (192 VGPR/AGPR, MFMA-native).
//                 Per step: 8x(ds_read A-frag) + 48 MFMA -> epilogue fully
//                 lane-local (z,r,ah share lane+reg) -> 1 barrier/step.
//                 h: bf16 in swizzled double-buffered LDS + fp32 reg carry.
// ws: [0,100663296) gx3 ; +786432 Wtb ; +786432 Upk ; +4KB xmask  (~102.2 MB)
// ---------------------------------------------------------------------------

typedef short short8 __attribute__((ext_vector_type(8)));
typedef float f32x4 __attribute__((ext_vector_type(4)));

__device__ __forceinline__ unsigned short f2bf(float f) {
  unsigned int u = __float_as_uint(f);
  return (unsigned short)((u + 0x7fffu + ((u >> 16) & 1u)) >> 16);  // RNE
}
__device__ __forceinline__ float blo(unsigned int u) { return __uint_as_float(u << 16); }
__device__ __forceinline__ float bhi(unsigned int u) { return __uint_as_float(u & 0xffff0000u); }
__device__ __forceinline__ float sigf(float x) {
  return __builtin_amdgcn_rcpf(1.f + __expf(-x));
}
__device__ __forceinline__ float tanhfast(float x) {
  return 1.f - 2.f * __builtin_amdgcn_rcpf(1.f + __expf(2.f * x));
}

// ---------------- k0a: Wtb[dir][c][k] = bf16(W[k][c]) -----------------------
__global__ void __launch_bounds__(256) wt_prep_kernel(const float* __restrict__ Wf,
                                                      const float* __restrict__ Wb,
                                                      unsigned short* __restrict__ Wtb) {
  int o = blockIdx.x * 256 + threadIdx.x;
  if (o >= 2 * 768 * 256) return;
  int dir = o / (768 * 256);
  int rem = o % (768 * 256);
  int c = rem / 256, k = rem % 256;
  const float* W = dir ? Wb : Wf;
  Wtb[o] = f2bf(W[(size_t)k * 768 + c]);
}

// ---------------- k0b: U -> MFMA B-fragments --------------------------------
// id = (((dir*8+w)*6+s)*8+kk)*64+lane ; frag elem e:
//   U[k = kk*32+(lane>>4)*8+e][gcol = (s>>1)*256 + w*32 + (s&1)*16 + (lane&15)]
__global__ void __launch_bounds__(256) u_prep_kernel(const float* __restrict__ Uf,
                                                     const float* __restrict__ Ub,
                                                     unsigned short* __restrict__ Upk) {
  int id = blockIdx.x * 256 + threadIdx.x;
  if (id >= 2 * 8 * 6 * 8 * 64) return;  // 49152
  int lane = id & 63;
  int kk = (id >> 6) & 7;
  int s = (id >> 9) % 6;
  int w = (id / (64 * 8 * 6)) & 7;
  int dir = id / (64 * 8 * 6 * 8);
  const float* U = dir ? Ub : Uf;
  int gcol = (s >> 1) * 256 + w * 32 + (s & 1) * 16 + (lane & 15);
  int k0 = kk * 32 + (lane >> 4) * 8;
  unsigned short* o = Upk + (size_t)id * 8;
#pragma unroll
  for (int e = 0; e < 8; ++e) o[e] = f2bf(U[(size_t)(k0 + e) * 768 + gcol]);
}

// ---------------- k0c: per-timestep mask bitmap -----------------------------
__global__ void __launch_bounds__(256) xmask_kernel(const int* __restrict__ x,
                                                    unsigned long long* __restrict__ xm) {
  int t = blockIdx.x * 256 + threadIdx.x;
  if (t >= 512) return;
  unsigned long long m = 0ull;
  for (int b = 0; b < 64; ++b)
    if (x[(size_t)b * 512 + t] != 0) m |= (1ull << b);
  xm[t] = m;
}

// ---------------- k1: gx3 = emb[x] @ W + bias, bf16 MFMA --------------------
// grid (256, 12): bx = 128-row tile (rows = b*512+t), by: dir = by>=6,
// c0 = (by%6)*128. Stores into the gru-epilogue layout.
__global__ void __launch_bounds__(256) gx_mfma_kernel(
    const int* __restrict__ x, const float* __restrict__ emb,
    const unsigned short* __restrict__ Wtb,
    const float* __restrict__ bfv, const float* __restrict__ bbv,
    unsigned short* __restrict__ gx3) {
  __shared__ __align__(16) unsigned short As[128 * 32];
  __shared__ __align__(16) unsigned short Bs[128 * 32];
  __shared__ int xid[128];

  int tid = threadIdx.x;
  int r0 = blockIdx.x * 128;
  int yt = blockIdx.y;
  int dir = (yt >= 6) ? 1 : 0;
  int c0 = (yt - dir * 6) * 128;
  const float* bv = dir ? bbv : bfv;
  const unsigned short* WtD = Wtb + (size_t)dir * 768 * 256;

  if (tid < 128) xid[tid] = x[r0 + tid];
  __syncthreads();

  int lane = tid & 63, w = tid >> 6;
  int wr = w >> 1, wc = w & 1;

  f32x4 acc[4][4] = {};

  for (int ks = 0; ks < 8; ++ks) {
#pragma unroll
    for (int i = 0; i < 2; ++i) {
      int s = tid + i * 256;
      int row = s >> 2, kslot = s & 3;
      int sw = kslot ^ ((row >> 2) & 3);
      const float* src = emb + (size_t)xid[row] * 256 + ks * 32 + kslot * 8;
      float4 f0 = *(const float4*)src;
      float4 f1 = *(const float4*)(src + 4);
      uint4 pa;
      pa.x = f2bf(f0.x) | ((unsigned)f2bf(f0.y) << 16);
      pa.y = f2bf(f0.z) | ((unsigned)f2bf(f0.w) << 16);
      pa.z = f2bf(f1.x) | ((unsigned)f2bf(f1.y) << 16);
      pa.w = f2bf(f1.z) | ((unsigned)f2bf(f1.w) << 16);
      *(uint4*)&As[row * 32 + sw * 8] = pa;
      uint4 pb = *(const uint4*)(WtD + (size_t)(c0 + row) * 256 + ks * 32 + kslot * 8);
      *(uint4*)&Bs[row * 32 + sw * 8] = pb;
    }
    __syncthreads();

    short8 a[4], b[4];
#pragma unroll
    for (int f = 0; f < 4; ++f) {
      int rowA = wr * 64 + f * 16 + (lane & 15);
      int swA = (lane >> 4) ^ ((rowA >> 2) & 3);
      a[f] = __builtin_bit_cast(short8, *(const uint4*)&As[rowA * 32 + swA * 8]);
      int rowB = wc * 64 + f * 16 + (lane & 15);
      int swB = (lane >> 4) ^ ((rowB >> 2) & 3);
      b[f] = __builtin_bit_cast(short8, *(const uint4*)&Bs[rowB * 32 + swB * 8]);
    }
#pragma unroll
    for (int fm = 0; fm < 4; ++fm)
#pragma unroll
      for (int fn = 0; fn < 4; ++fn)
        acc[fm][fn] = __builtin_amdgcn_mfma_f32_16x16x32_bf16(a[fm], b[fn], acc[fm][fn], 0, 0, 0);
    __syncthreads();
  }

#pragma unroll
  for (int fn = 0; fn < 4; ++fn) {
    int col = c0 + wc * 64 + fn * 16 + (lane & 15);
    float bias = bv[col] + (col < 512 ? bv[768 + col] : 0.f);
    int g = col >> 8, u = col & 255;
    int w2 = u >> 5, tts = (u >> 4) & 1, cl2 = u & 15;
    int slot = g * 2 + tts;
#pragma unroll
    for (int fm = 0; fm < 4; ++fm) {
      int rowb = r0 + wr * 64 + fm * 16 + (lane >> 4) * 4;
#pragma unroll
      for (int q = 0; q < 4; ++q) {
        int row = rowb + q;
        int b = row >> 9, tt2 = row & 511;
        int i = b & 15, bg2 = b >> 4;
        int lane2 = ((i >> 2) << 4) | cl2, q2 = i & 3;
        size_t idx = (((((size_t)dir * 512 + tt2) * 4 + bg2) * 8 + w2) * 6 + slot) * 256
                     + lane2 * 4 + q2;
        gx3[idx] = f2bf(acc[fm][fn][q] + bias);
      }
    }
  }
}

// ---------------- k2: MFMA recurrence ---------------------------------------
__global__ void __launch_bounds__(512, 2) gru_kernel(
    const unsigned short* __restrict__ Upk,
    const unsigned short* __restrict__ gx3,
    const unsigned long long* __restrict__ xmask,
    const float* __restrict__ bfv, const float* __restrict__ bbv,
    float* __restrict__ out) {
  int dir = blockIdx.x >> 2, bg = blockIdx.x & 3;
  int tid = threadIdx.x;
  int w = tid >> 6, lane = tid & 63;
  int lq = lane >> 4, cl = lane & 15;

  // h[16 rows][256 units] bf16, XOR-swizzled ((row&7)<<4), double-buffered
  __shared__ __align__(16) unsigned short h_lds[2][4096];

  // --- resident U B-fragments: slot s (z0,z1,r0,r1,h0,h1) x kk ---
  short8 Uf[6][8];
  {
    const unsigned short* ub = Upk + (size_t)(dir * 8 + w) * 24576 + lane * 8;
#pragma unroll
    for (int s = 0; s < 6; ++s)
#pragma unroll
      for (int kk = 0; kk < 8; ++kk)
        Uf[s][kk] = __builtin_bit_cast(short8, *(const uint4*)(ub + (s * 8 + kk) * 512));
  }

  { uint4 z4 = {0u, 0u, 0u, 0u}; ((uint4*)&h_lds[0][0])[tid] = z4; }  // 512*16B = 8KB

  int u0 = w * 32 + cl;                       // unit for tts=0 (tts=1: +16)
  const float* bv = dir ? bbv : bfv;
  float brh0 = bv[1280 + u0], brh1 = bv[1280 + u0 + 16];
  int ib = bg * 16 + lq * 4;                  // batch for q=0
  float h_old0[4] = {0.f, 0.f, 0.f, 0.f};     // fp32 carry, tts=0
  float h_old1[4] = {0.f, 0.f, 0.f, 0.f};     // tts=1

  // h_lds write bases (q=0), swizzle split: mask = ((lq&1)<<6) ^ (q<<4)
  int swzb = (lq & 1) << 6;
  int wb0 = ((lq * 4) * 512 + u0 * 2) ^ swzb;
  int wb1 = ((lq * 4) * 512 + (u0 + 16) * 2) ^ swzb;
  int abase = cl * 512 + lq * 16;             // A-read base (pre-XOR)
  int amask = (cl & 7) << 4;

  // gx3 per-lane base: + (dir*512+t)*49152 + slot*256
  const unsigned short* gwb = gx3 + ((size_t)bg * 8 + w) * 1536 + lane * 4;

  // prologue: prefetch step 0's gx
  int t0 = dir ? 511 : 0;
  uint2 gq[6];
  {
    const unsigned short* g = gwb + (size_t)(dir * 512 + t0) * 49152;
#pragma unroll
    for (int s = 0; s < 6; ++s) gq[s] = *(const uint2*)(g + s * 256);
  }
  __syncthreads();

  int cur = 0;
  for (int step = 0; step < 512; ++step) {
    int tcur = dir ? (511 - step) : step;
    // prefetch next step's gx (consumed next iteration; HBM latency hidden)
    int sn = (step < 511) ? step + 1 : 511;
    int tn = dir ? (511 - sn) : sn;
    uint2 gn[6];
    {
      const unsigned short* g = gwb + (size_t)(dir * 512 + tn) * 49152;
#pragma unroll
      for (int s = 0; s < 6; ++s) gn[s] = *(const uint2*)(g + s * 256);
    }
    unsigned long long xm = xmask[tcur];

    // --- MFMA phase: acc[s] = h @ U[slot s] ---
    f32x4 acc[6];
#pragma unroll
    for (int s = 0; s < 6; ++s) acc[s] = (f32x4){0.f, 0.f, 0.f, 0.f};
    const char* hb = (const char*)&h_lds[cur][0];
#pragma unroll
    for (int kk = 0; kk < 8; ++kk) {
      short8 a = __builtin_bit_cast(short8,
                   *(const uint4*)(hb + ((abase + kk * 64) ^ amask)));
#pragma unroll
      for (int s = 0; s < 6; ++s)
        acc[s] = __builtin_amdgcn_mfma_f32_16x16x32_bf16(a, Uf[s][kk], acc[s], 0, 0, 0);
    }

    // --- epilogue: fully lane-local ---
    char* hw = (char*)&h_lds[cur ^ 1][0];
#pragma unroll
    for (int tts = 0; tts < 2; ++tts) {
      uint2 gz = gq[0 + tts], gr = gq[2 + tts], gh = gq[4 + tts];
      float brh = tts ? brh1 : brh0;
      int wb = tts ? wb1 : wb0;
      int uu = u0 + tts * 16;
      float* ho_arr = tts ? h_old1 : h_old0;
#pragma unroll
      for (int q = 0; q < 4; ++q) {
        float gxz = (q == 0) ? blo(gz.x) : (q == 1) ? bhi(gz.x) : (q == 2) ? blo(gz.y) : bhi(gz.y);
        float gxr = (q == 0) ? blo(gr.x) : (q == 1) ? bhi(gr.x) : (q == 2) ? blo(gr.y) : bhi(gr.y);
        float gxh = (q == 0) ? blo(gh.x) : (q == 1) ? bhi(gh.x) : (q == 2) ? blo(gh.y) : bhi(gh.y);
        float zp = acc[0 + tts][q] + gxz;
        float rp = acc[2 + tts][q] + gxr;
        float ah = acc[4 + tts][q];
        float z = sigf(zp), r = sigf(rp);
        float hh = tanhfast(gxh + r * (ah + brh));
        float ho = ho_arr[q];
        float hn = hh + z * (ho - hh);
        unsigned int keep = (unsigned int)(xm >> (ib + q)) & 1u;
        hn = keep ? hn : ho;
        ho_arr[q] = hn;
        *(unsigned short*)(hw + ((wb + q * 512) ^ (q << 4))) = f2bf(hn);
        atomicAdd(out + (((size_t)(ib + q)) << 17) + tcur * 256 + uu, hn);
      }
    }
    __syncthreads();
#pragma unroll
    for (int s = 0; s < 6; ++s) gq[s] = gn[s];
    cur ^= 1;
  }
}

// ---------------------------------------------------------------------------
extern "C" void kernel_launch(void* const* d_in, const int* in_sizes, int n_in,
                              void* d_out, int out_size, void* d_ws, size_t ws_size,
                              hipStream_t stream) {
  const int*   x   = (const int*)d_in[0];
  const float* emb = (const float*)d_in[1];
  const float* Wf  = (const float*)d_in[2];
  const float* Uf  = (const float*)d_in[3];
  const float* bf_ = (const float*)d_in[4];
  const float* Wb  = (const float*)d_in[5];
  const float* Ub  = (const float*)d_in[6];
  const float* bb_ = (const float*)d_in[7];
  float* out = (float*)d_out;

  unsigned short* gx3 = (unsigned short*)d_ws;                                   // 100663296 B
  unsigned short* Wtb = (unsigned short*)((char*)d_ws + 100663296);              // 786432 B
  unsigned short* Upk = (unsigned short*)((char*)d_ws + 100663296 + 786432);     // 786432 B
  unsigned long long* xm = (unsigned long long*)((char*)d_ws + 100663296 + 2 * 786432);  // 4 KB

  hipMemsetAsync(d_out, 0, (size_t)out_size * sizeof(float), stream);

  wt_prep_kernel<<<1536, 256, 0, stream>>>(Wf, Wb, Wtb);
  u_prep_kernel<<<192, 256, 0, stream>>>(Uf, Ub, Upk);
  xmask_kernel<<<2, 256, 0, stream>>>(x, xm);
  gx_mfma_kernel<<<dim3(256, 12), 256, 0, stream>>>(x, emb, Wtb, bf_, bb_, gx3);
  gru_kernel<<<8, 512, 0, stream>>>(Upk, gx3, xm, bf_, bb_, out);
}

// Round 7
// 846.855 us; speedup vs baseline: 1.8707x; 1.8707x over previous
//
#include <hip/hip_runtime.h>
#include <hip/hip_bf16.h>

// ---------------------------------------------------------------------------
// Bidirectional GRU encoder (Keras reset_after=true), B=64 S=512 U=256 V=32000
// Round 7: round-2/3 VALU recurrence + the launch_bounds fix.
//   __launch_bounds__(512, 1): 1 block/CU min -> 8 waves -> 2 waves/SIMD ->
//   VGPR cap 256. The 192-uint per-thread U file (~240 regs total) finally
//   fits in architectural VGPRs (r2/r4/r5 failed at caps 128/64: AGPR+scratch).
//   k0a wt_prep : W fp32 -> Wtb [dir][768][256] bf16 (transposed)
//   k0b u_prep  : U fp32 -> per-thread fp16-pair blobs (768 B each)
//   k1  gx_mfma : gx = emb[x] @ W + b_in (+ b_rec for z,r), bf16 MFMA 16x16x32
//   k2  gru     : 128 wgs = (dir,batch) = 1 chain per CU, 512 thr.
//                 thread (j = t>>1, ks = t&1): k-slice 128, 192 dot2/step.
//                 h fp16 pairs in LDS [2][144] (region pad 8 -> disjoint bank
//                 quads, conflict-free), double-buffered, 1 barrier/step,
//                 gx software-pipelined 1 step ahead, atomicAdd merge.
// ws: [0,100663296) gx ; +786432 Wtb ; +786432 Upk   (~102.2 MB)
// ---------------------------------------------------------------------------

typedef _Float16 half2v __attribute__((ext_vector_type(2)));
typedef short short8 __attribute__((ext_vector_type(8)));
typedef float f32x4 __attribute__((ext_vector_type(4)));

__device__ __forceinline__ unsigned short f2bf(float f) {
  unsigned int u = __float_as_uint(f);
  return (unsigned short)((u + 0x7fffu + ((u >> 16) & 1u)) >> 16);  // RNE
}
__device__ __forceinline__ float bf2f(unsigned short v) {
  return __uint_as_float((unsigned int)v << 16);
}
__device__ __forceinline__ unsigned int packf16(float a, float b) {
  half2v v = {(_Float16)a, (_Float16)b};
  return __builtin_bit_cast(unsigned int, v);
}
__device__ __forceinline__ float dot2(unsigned int u, unsigned int hv, float acc) {
#if __has_builtin(__builtin_amdgcn_fdot2)
  return __builtin_amdgcn_fdot2(__builtin_bit_cast(half2v, u),
                                __builtin_bit_cast(half2v, hv), acc, false);
#else
  half2v a = __builtin_bit_cast(half2v, u), b = __builtin_bit_cast(half2v, hv);
  return acc + (float)a.x * (float)b.x + (float)a.y * (float)b.y;
#endif
}
__device__ __forceinline__ float sigf(float x) {
  return __builtin_amdgcn_rcpf(1.f + __expf(-x));
}
__device__ __forceinline__ float tanhfast(float x) {
  return 1.f - 2.f * __builtin_amdgcn_rcpf(1.f + __expf(2.f * x));
}

// ---------------- k0a: Wtb[dir][c][k] = bf16(W[k][c]) -----------------------
__global__ void __launch_bounds__(256) wt_prep_kernel(const float* __restrict__ Wf,
                                                      const float* __restrict__ Wb,
                                                      unsigned short* __restrict__ Wtb) {
  int o = blockIdx.x * 256 + threadIdx.x;
  if (o >= 2 * 768 * 256) return;
  int dir = o / (768 * 256);
  int rem = o % (768 * 256);
  int c = rem / 256, k = rem % 256;
  const float* W = dir ? Wb : Wf;
  Wtb[o] = f2bf(W[(size_t)k * 768 + c]);
}

// ---------------- k0b: per-thread U blobs (round-7 order) -------------------
// id = dir*512 + t, t = j*2 + ks. blob[192]: [uz 64 | ur 64 | uh 64];
// uz[p] = pack(U[ks*128+2p][j], U[ks*128+2p+1][j]); ur: col 256+j; uh: 512+j.
__global__ void __launch_bounds__(256) u_prep_kernel(const float* __restrict__ Uf,
                                                     const float* __restrict__ Ub,
                                                     unsigned int* __restrict__ Upk) {
  int id = blockIdx.x * 256 + threadIdx.x;
  if (id >= 1024) return;
  int dir = id >> 9, t = id & 511;
  int j = t >> 1, ks = t & 1;
  const float* U = dir ? Ub : Uf;
  unsigned int* o = Upk + (size_t)id * 192;
#pragma unroll
  for (int g = 0; g < 3; ++g) {
    int col = g * 256 + j;
#pragma unroll
    for (int p = 0; p < 64; ++p) {
      int k = ks * 128 + 2 * p;
      o[g * 64 + p] = packf16(U[(size_t)k * 768 + col], U[(size_t)(k + 1) * 768 + col]);
    }
  }
}

// ---------------- k1: gx = emb[x] @ W + bias, bf16 MFMA ---------------------
__global__ void __launch_bounds__(256) gx_mfma_kernel(
    const int* __restrict__ x, const float* __restrict__ emb,
    const unsigned short* __restrict__ Wtb,
    const float* __restrict__ bfv, const float* __restrict__ bbv,
    unsigned short* __restrict__ gx) {
  __shared__ __align__(16) unsigned short As[128 * 32];
  __shared__ __align__(16) unsigned short Bs[128 * 32];
  __shared__ int xid[128];

  int tid = threadIdx.x;
  int r0 = blockIdx.x * 128;
  int yt = blockIdx.y;
  int dir = (yt >= 6) ? 1 : 0;
  int c0 = (yt - dir * 6) * 128;
  const float* bv = dir ? bbv : bfv;
  const unsigned short* WtD = Wtb + (size_t)dir * 768 * 256;

  if (tid < 128) xid[tid] = x[r0 + tid];
  __syncthreads();

  int lane = tid & 63, w = tid >> 6;
  int wr = w >> 1, wc = w & 1;

  f32x4 acc[4][4] = {};

  for (int ks = 0; ks < 8; ++ks) {
#pragma unroll
    for (int i = 0; i < 2; ++i) {
      int s = tid + i * 256;
      int row = s >> 2, kslot = s & 3;
      int sw = kslot ^ ((row >> 2) & 3);
      const float* src = emb + (size_t)xid[row] * 256 + ks * 32 + kslot * 8;
      float4 f0 = *(const float4*)src;
      float4 f1 = *(const float4*)(src + 4);
      uint4 pa;
      pa.x = f2bf(f0.x) | ((unsigned)f2bf(f0.y) << 16);
      pa.y = f2bf(f0.z) | ((unsigned)f2bf(f0.w) << 16);
      pa.z = f2bf(f1.x) | ((unsigned)f2bf(f1.y) << 16);
      pa.w = f2bf(f1.z) | ((unsigned)f2bf(f1.w) << 16);
      *(uint4*)&As[row * 32 + sw * 8] = pa;
      uint4 pb = *(const uint4*)(WtD + (size_t)(c0 + row) * 256 + ks * 32 + kslot * 8);
      *(uint4*)&Bs[row * 32 + sw * 8] = pb;
    }
    __syncthreads();

    short8 a[4], b[4];
#pragma unroll
    for (int f = 0; f < 4; ++f) {
      int rowA = wr * 64 + f * 16 + (lane & 15);
      int swA = (lane >> 4) ^ ((rowA >> 2) & 3);
      a[f] = __builtin_bit_cast(short8, *(const uint4*)&As[rowA * 32 + swA * 8]);
      int rowB = wc * 64 + f * 16 + (lane & 15);
      int swB = (lane >> 4) ^ ((rowB >> 2) & 3);
      b[f] = __builtin_bit_cast(short8, *(const uint4*)&Bs[rowB * 32 + swB * 8]);
    }
#pragma unroll
    for (int fm = 0; fm < 4; ++fm)
#pragma unroll
      for (int fn = 0; fn < 4; ++fn)
        acc[fm][fn] = __builtin_amdgcn_mfma_f32_16x16x32_bf16(a[fm], b[fn], acc[fm][fn], 0, 0, 0);
    __syncthreads();
  }

#pragma unroll
  for (int fn = 0; fn < 4; ++fn) {
    int col = c0 + wc * 64 + fn * 16 + (lane & 15);
    float bias = bv[col] + (col < 512 ? bv[768 + col] : 0.f);
#pragma unroll
    for (int fm = 0; fm < 4; ++fm) {
      int rowb = r0 + wr * 64 + fm * 16 + (lane >> 4) * 4;
#pragma unroll
      for (int q = 0; q < 4; ++q) {
        gx[((size_t)dir * 32768 + rowb + q) * 768 + col] = f2bf(acc[fm][fn][q] + bias);
      }
    }
  }
}

// ---------------- k2: recurrence (VALU dot2, U resident in VGPRs) -----------
__global__ void __launch_bounds__(512, 1) gru_kernel(
    const unsigned int* __restrict__ Upk,    // [2*512][192] fp16 pairs
    const unsigned short* __restrict__ gx,   // [2][32768][768] bf16
    const int* __restrict__ x,
    const float* __restrict__ bfv, const float* __restrict__ bbv,
    float* __restrict__ out) {
  int wg = blockIdx.x;
  int dir = wg >> 6, b = wg & 63;
  int t = threadIdx.x;
  int j = t >> 1;            // unit 0..255
  int ks = t & 1;            // k-half: k in [128ks, 128ks+128)

  // h as fp16 pairs: region ks at ints [ks*72, ks*72+64), pad 8 ->
  // the wave's two b128 addresses hit disjoint bank quads. Double-buffered.
  __shared__ unsigned int h_buf[2][144];

  const float brh = (dir ? bbv : bfv)[768 + 512 + j];
  const unsigned short* gxd = gx + ((size_t)dir * 32768 + (size_t)b * 512) * 768;
  const int* xb = x + b * 512;
  float* outb = out + ((size_t)b << 17);

  // one-time: 48 coalesced uint4 loads of this thread's U blob
  unsigned int uz[64], ur[64], uh[64];
  {
    const uint4* us = (const uint4*)(Upk + (size_t)((dir << 9) | t) * 192);
#pragma unroll
    for (int q = 0; q < 16; ++q) {
      uint4 v = us[q];
      uz[4 * q] = v.x; uz[4 * q + 1] = v.y; uz[4 * q + 2] = v.z; uz[4 * q + 3] = v.w;
    }
#pragma unroll
    for (int q = 0; q < 16; ++q) {
      uint4 v = us[16 + q];
      ur[4 * q] = v.x; ur[4 * q + 1] = v.y; ur[4 * q + 2] = v.z; ur[4 * q + 3] = v.w;
    }
#pragma unroll
    for (int q = 0; q < 16; ++q) {
      uint4 v = us[32 + q];
      uh[4 * q] = v.x; uh[4 * q + 1] = v.y; uh[4 * q + 2] = v.z; uh[4 * q + 3] = v.w;
    }
  }
  if (t < 144) h_buf[0][t] = 0u;
  __syncthreads();

  // prologue: preload step 0's gx + mask
  int tt0 = dir ? 511 : 0;
  const unsigned short* g0 = gxd + (size_t)tt0 * 768;
  float gz = bf2f(g0[j]), gr = bf2f(g0[256 + j]), gh = bf2f(g0[512 + j]);
  int xv = xb[tt0];

  float hj = 0.f;
  int cur = 0;
  for (int step = 0; step < 512; ++step) {
    int tcur = dir ? (511 - step) : step;
    // prefetch next step (latency hidden under dot loop)
    float gz_n = 0.f, gr_n = 0.f, gh_n = 0.f;
    int xv_n = 0;
    if (step < 511) {
      int tn = dir ? (510 - step) : (step + 1);
      const unsigned short* gn = gxd + (size_t)tn * 768;
      gz_n = bf2f(gn[j]); gr_n = bf2f(gn[256 + j]); gh_n = bf2f(gn[512 + j]);
      xv_n = xb[tn];
    }

    float az0 = 0.f, az1 = 0.f, ar0 = 0.f, ar1 = 0.f, ah0 = 0.f, ah1 = 0.f;
    const unsigned int* hb = &h_buf[cur][ks * 72];
#pragma unroll
    for (int c = 0; c < 16; ++c) {
      uint4 hv = *(const uint4*)&hb[c * 4];   // 2 distinct addrs/wave, disjoint banks
      float& az = (c & 1) ? az1 : az0;
      float& ar = (c & 1) ? ar1 : ar0;
      float& ah = (c & 1) ? ah1 : ah0;
      az = dot2(uz[c * 4 + 0], hv.x, az);
      az = dot2(uz[c * 4 + 1], hv.y, az);
      az = dot2(uz[c * 4 + 2], hv.z, az);
      az = dot2(uz[c * 4 + 3], hv.w, az);
      ar = dot2(ur[c * 4 + 0], hv.x, ar);
      ar = dot2(ur[c * 4 + 1], hv.y, ar);
      ar = dot2(ur[c * 4 + 2], hv.z, ar);
      ar = dot2(ur[c * 4 + 3], hv.w, ar);
      ah = dot2(uh[c * 4 + 0], hv.x, ah);
      ah = dot2(uh[c * 4 + 1], hv.y, ah);
      ah = dot2(uh[c * 4 + 2], hv.z, ah);
      ah = dot2(uh[c * 4 + 3], hv.w, ah);
    }
    float az = az0 + az1; az += __shfl_xor(az, 1);
    float ar = ar0 + ar1; ar += __shfl_xor(ar, 1);
    float ah = ah0 + ah1; ah += __shfl_xor(ah, 1);

    float z = sigf(gz + az);
    float r = sigf(gr + ar);
    float hh = tanhfast(gh + r * (ah + brh));
    float hn = hh + z * (hj - hh);
    hn = (xv == 0) ? hj : hn;                  // masked: carry state

    float hpart = __shfl_xor(hn, 2);           // unit j^1's hn
    if ((t & 3) == 0) {
      int m = t >> 2;                          // h-pair index 0..127
      h_buf[cur ^ 1][(m >> 6) * 72 + (m & 63)] = packf16(hn, hpart);
    }
    __syncthreads();                           // single barrier per step

    if (ks == 0) atomicAdd(&outb[(size_t)tcur * 256 + j], hn);
    hj = hn; gz = gz_n; gr = gr_n; gh = gh_n; xv = xv_n;
    cur ^= 1;
  }
}

// ---------------------------------------------------------------------------
extern "C" void kernel_launch(void* const* d_in, const int* in_sizes, int n_in,
                              void* d_out, int out_size, void* d_ws, size_t ws_size,
                              hipStream_t stream) {
  const int*   x   = (const int*)d_in[0];
  const float* emb = (const float*)d_in[1];
  const float* Wf  = (const float*)d_in[2];
  const float* Uf  = (const float*)d_in[3];
  const float* bf_ = (const float*)d_in[4];
  const float* Wb  = (const float*)d_in[5];
  const float* Ub  = (const float*)d_in[6];
  const float* bb_ = (const float*)d_in[7];
  float* out = (float*)d_out;

  unsigned short* gxp = (unsigned short*)d_ws;                        // 100663296 B
  unsigned short* Wtb = (unsigned short*)((char*)d_ws + 100663296);   // 786432 B
  unsigned int*   Upk = (unsigned int*)((char*)d_ws + 100663296 + 786432);  // 786432 B

  hipMemsetAsync(d_out, 0, (size_t)out_size * sizeof(float), stream);

  wt_prep_kernel<<<1536, 256, 0, stream>>>(Wf, Wb, Wtb);
  u_prep_kernel<<<4, 256, 0, stream>>>(Uf, Ub, Upk);
  gx_mfma_kernel<<<dim3(256, 12), 256, 0, stream>>>(x, emb, Wtb, bf_, bb_, gxp);
  gru_kernel<<<128, 512, 0, stream>>>(Upk, gxp, x, bf_, bb_, out);
}